// Round 15
// baseline (350.739 us; speedup 1.0000x reference)
//
#include <hip/hip_runtime.h>
#include <math.h>

// ComplexGaussianRasterizer — home-bucket bin + per-tile LDS-atomic splat.
// 3 nodes:
//   memset:  zero homecnt (128 KB).
//   K1 build: per gaussian -> 48B record at rec[g] (coalesced); append
//             (pb, id) to its 4^3 home cell's fixed-HCAP bucket (1 atomic).
//   K2 splat: one 512-thread block (8 waves) per 16^3 tile. Phase 1: zero
//             34.8KB padded LDS accumulator. Phase 2: pull candidates from
//             the 6^3 neighbor homes (9 iters x 3 homes x 20 lanes per wave),
//             window-test, ballot-compact into block-shared id list.
//             Phase 3: each wave splats its candidates: lanes = the 216
//             footprint offsets (4 iters), in-tile masked, exp2 + 2 LDS
//             atomics (gated at arg > -14.43 ~ w > 4.5e-5 << tolerance).
//             Phase 4: coalesced float2 writeout (tiles partition the grid).

#define RES    128
#define NSBA   32
#define NTILE  (NSBA * NSBA * NSBA)   // 32768 home cells
#define RECSZ  12                     // floats per record (48 B)
#define HCAP   20                     // home-bucket capacity (lambda ~3.05)
#define IDCAP  1024                   // per-tile candidate cap (lambda ~660)
#define TPLANE 4352                   // 16*16*17 padded floats per channel

// ---------------- record builder (quad coeffs scaled by log2e) -------------
__device__ __forceinline__ void build_record_at(
    const float* means, const float* opacities, const float* scales,
    const float* rotations, const float* phases, const float* phases_add,
    float* recdst, int g, int* bxo, int* byo, int* bzo)
{
    const float LB   = -1.0f;
    const float VOX  = 2.0f / 128.0f;
    const float L2E  = 1.4426950408889634f;

    float mx = means[g*3+0], my = means[g*3+1], mz = means[g*3+2];
    float op = opacities[g];
    float sx = scales[g*3+0], sy = scales[g*3+1], sz = scales[g*3+2];
    float qw = rotations[g*4+0], qx = rotations[g*4+1],
          qy = rotations[g*4+2], qz = rotations[g*4+3];
    float ph = phases[g], pa = phases_add[g];

    float qn = rsqrtf(qw*qw + qx*qx + qy*qy + qz*qz);
    qw *= qn; qx *= qn; qy *= qn; qz *= qn;

    float r00 = 1.0f - 2.0f*(qy*qy + qz*qz);
    float r01 = 2.0f*(qx*qy - qw*qz);
    float r02 = 2.0f*(qx*qz + qw*qy);
    float r10 = 2.0f*(qx*qy + qw*qz);
    float r11 = 1.0f - 2.0f*(qx*qx + qz*qz);
    float r12 = 2.0f*(qy*qz - qw*qx);
    float r20 = 2.0f*(qx*qz - qw*qy);
    float r21 = 2.0f*(qy*qz + qw*qx);
    float r22 = 1.0f - 2.0f*(qx*qx + qy*qy);

    float m00 = r00*sx, m01 = r01*sy, m02 = r02*sz;
    float m10 = r10*sx, m11 = r11*sy, m12 = r12*sz;
    float m20 = r20*sx, m21 = r21*sy, m22 = r22*sz;

    float a = m00*m00 + m01*m01 + m02*m02;
    float b = m00*m10 + m01*m11 + m02*m12;
    float c = m00*m20 + m01*m21 + m02*m22;
    float d = m10*m10 + m11*m11 + m12*m12;
    float e = m10*m20 + m11*m21 + m12*m22;
    float f = m20*m20 + m21*m21 + m22*m22;

    float A = d*f - e*e;
    float B = c*e - b*f;
    float C = b*e - c*d;
    float det  = a*A + b*B + c*C;
    float idet = L2E / det;            // fold log2e into all quad coeffs

    float n00 = -0.5f * A * idet;
    float n01 = -B * idet;
    float n02 = -C * idet;
    float n11 = -0.5f * (a*f - c*c) * idet;
    float n12 = -(b*c - a*e) * idet;
    float n22 = -0.5f * (a*d - b*b) * idet;

    int bx = (int)floorf((mx - LB) * 64.0f) - 3;
    int by = (int)floorf((my - LB) * 64.0f) - 3;
    int bz = (int)floorf((mz - LB) * 64.0f) - 3;
    unsigned pb = ((unsigned)(bx + 4) << 16) | ((unsigned)(by + 4) << 8) |
                  (unsigned)(bz + 4);

    float sr, cr;
    __sincosf(ph, &sr, &cr);
    float wr = op * cr;
    float wi = op * (sr + pa);

    float fx = LB + 0.5f * VOX - mx;
    float fy = LB + 0.5f * VOX - my;
    float fz = LB + 0.5f * VOX - mz;

    float4* rp = reinterpret_cast<float4*>(recdst);
    rp[0] = make_float4(n00, n01, n02, n11);
    rp[1] = make_float4(n12, n22, fx, fy);
    rp[2] = make_float4(fz, wr, wi, __uint_as_float(pb));
    *bxo = bx; *byo = by; *bzo = bz;
}

// ---------------- K1: build records + home-bucket append ----------------
__global__ __launch_bounds__(256) void cgr_build(
    const float* __restrict__ means, const float* __restrict__ opacities,
    const float* __restrict__ scales, const float* __restrict__ rotations,
    const float* __restrict__ phases, const float* __restrict__ phases_add,
    float* __restrict__ rec, int* __restrict__ homecnt,
    unsigned* __restrict__ hpb, int* __restrict__ hlist, int N)
{
    int g = blockIdx.x * 256 + threadIdx.x;
    if (g >= N) return;
    int bx, by, bz;
    build_record_at(means, opacities, scales, rotations, phases, phases_add,
                    rec + (size_t)g * RECSZ, g, &bx, &by, &bz);
    unsigned pb = ((unsigned)(bx + 4) << 16) | ((unsigned)(by + 4) << 8) |
                  (unsigned)(bz + 4);
    int hx = min(max(bx, 0), RES - 1) >> 2;
    int hy = min(max(by, 0), RES - 1) >> 2;
    int hz = min(max(bz, 0), RES - 1) >> 2;
    int h = (hx * NSBA + hy) * NSBA + hz;
    int slot = atomicAdd(&homecnt[h], 1);
    if (slot < HCAP) {
        hpb[h * HCAP + slot]   = pb;
        hlist[h * HCAP + slot] = g;
    }
}

// ---------------- K2: per-tile candidate pull + LDS-atomic splat ----------
__global__ __launch_bounds__(512) void cgr_splat(
    const float* __restrict__ rec,
    const int* __restrict__ homecnt,
    const unsigned* __restrict__ hpb,
    const int* __restrict__ hlist,
    float* __restrict__ grid)
{
    __shared__ float acc[2 * TPLANE];       // padded accum: l=(x*16+y)*17+z
    __shared__ float sbuf[8][64 * RECSZ];   // wave-private record staging
    __shared__ int   idb[IDCAP];
    __shared__ int   ncand;

    const float VOXC = 2.0f / 128.0f;

    int tid  = threadIdx.x;
    int wave = tid >> 6;
    int lane = tid & 63;

    int bid = blockIdx.x;
    int T = (bid & 7) * 64 + (bid >> 3);    // XCD-chunked swizzle, 512 tiles
    int tx0 = (T >> 6) << 4;
    int ty0 = ((T >> 3) & 7) << 4;
    int tz0 = (T & 7) << 4;

    // ---- phase 1: zero accumulator ----
    for (int i = tid; i < 2 * TPLANE; i += 512) acc[i] = 0.0f;
    if (tid == 0) ncand = 0;
    __syncthreads();

    // ---- phase 2: candidate pull from 6^3 neighbor homes ----
    // overlap: bx in [t0-5, t0+15]  <=>  px = bx+4 - (t0-1) in [0,20]
    int hx0 = (tx0 >> 2) - 2;
    int hy0 = (ty0 >> 2) - 2;
    int hz0 = (tz0 >> 2) - 2;
    {
        int grp  = lane / 20;               // 0..3 (lanes 60..63 idle)
        int slot = lane - grp * 20;
        bool lv  = grp < 3;
        for (int it = 0; it < 9; ++it) {
            int idx = wave * 27 + it * 3 + grp;   // 0..215
            int dhx = idx / 36;
            int rm  = idx - dhx * 36;
            int dhy = rm / 6;
            int dhz = rm - dhy * 6;
            int hx = hx0 + dhx, hy = hy0 + dhy, hz = hz0 + dhz;
            bool hv = lv & (hx >= 0) & (hy >= 0) & (hz >= 0);
            int h = hv ? (hx * NSBA + hy) * NSBA + hz : 0;
            int cnt = hv ? min(homecnt[h], HCAP) : 0;
            bool pass = slot < cnt;
            unsigned pb = 0u;
            int id = 0;
            if (pass) {
                pb = hpb[h * HCAP + slot];
                id = hlist[h * HCAP + slot];
            }
            if (pass) {
                pass = ((unsigned)((int)((pb >> 16) & 255u) - (tx0 - 1)) <= 20u) &
                       ((unsigned)((int)((pb >> 8) & 255u)  - (ty0 - 1)) <= 20u) &
                       ((unsigned)((int)(pb & 255u)         - (tz0 - 1)) <= 20u);
            }
            unsigned long long mm = __ballot(pass);
            int tot = (int)__popcll(mm);
            int base = 0;
            if (lane == 0 && tot) base = atomicAdd(&ncand, tot);
            base = __shfl(base, 0);
            if (pass) {
                int pos = base + (int)__popcll(mm & ((1ull << lane) - 1ull));
                if (pos < IDCAP) idb[pos] = id;
            }
        }
    }
    __syncthreads();
    int n = min(ncand, IDCAP);

    // ---- phase 3: splat (lanes = footprint offsets, 4 iterations) ----
    int   oxi[4], oyi[4], ozi[4];
    float oxf[4], oyf[4], ozf[4];
    #pragma unroll
    for (int t = 0; t < 4; ++t) {
        int off = lane + (t << 6);
        if (off > 215) off = 215;
        oxi[t] = off / 36;
        int rr = off - oxi[t] * 36;
        oyi[t] = rr / 6;
        ozi[t] = rr - oyi[t] * 6;
        oxf[t] = (float)oxi[t];
        oyf[t] = (float)oyi[t];
        ozf[t] = (float)ozi[t];
    }
    const bool tail = lane < 24;

    float* sb = sbuf[wave];
    for (int c0 = wave * 64; c0 < n; c0 += 512) {
        int m = min(64, n - c0);
        if (lane < m) {
            int id = idb[c0 + lane];
            const float4* rp =
                reinterpret_cast<const float4*>(rec + (size_t)id * RECSZ);
            float4 v0 = rp[0], v1 = rp[1], v2 = rp[2];
            float4* dst = reinterpret_cast<float4*>(sb + lane * RECSZ);
            dst[0] = v0; dst[1] = v1; dst[2] = v2;
        }
        // wave-private staging: no barrier needed
        for (int kk = 0; kk < m; ++kk) {
            const float4* rp = reinterpret_cast<const float4*>(sb + kk * RECSZ);
            float4 A0 = rp[0], A1 = rp[1], A2 = rp[2];
            unsigned pb = __float_as_uint(A2.w);
            int bx = (int)((pb >> 16) & 255u) - 4;
            int by = (int)((pb >> 8) & 255u) - 4;
            int bz = (int)(pb & 255u) - 4;
            int bxt = bx - tx0, byt = by - ty0, bzt = bz - tz0;
            float cx = fmaf((float)bx, VOXC, A1.z);
            float cy = fmaf((float)by, VOXC, A1.w);
            float cz = fmaf((float)bz, VOXC, A2.x);

            #pragma unroll
            for (int t = 0; t < 4; ++t) {
                if (t < 3 || tail) {
                    int lx = bxt + oxi[t];
                    int ly = byt + oyi[t];
                    int lz = bzt + ozi[t];
                    if ((unsigned)lx < 16u && (unsigned)ly < 16u &&
                        (unsigned)lz < 16u) {
                        float dx = fmaf(oxf[t], VOXC, cx);
                        float dy = fmaf(oyf[t], VOXC, cy);
                        float dz = fmaf(ozf[t], VOXC, cz);
                        float arg = dx * (A0.x * dx + A0.y * dy + A0.z * dz)
                                  + dy * (A0.w * dy + A1.x * dz)
                                  + dz * (A1.y * dz);
                        if (arg > -14.43f) {   // w > 4.5e-5 << 0.058 tolerance
                            float w = exp2f(arg);
                            int l = (lx * 16 + ly) * 17 + lz;
                            atomicAdd(&acc[l],          w * A2.y);
                            atomicAdd(&acc[TPLANE + l], w * A2.z);
                        }
                    }
                }
            }
        }
    }
    __syncthreads();

    // ---- phase 4: coalesced writeout (tiles partition the grid) ----
    #pragma unroll
    for (int q = 0; q < 8; ++q) {
        int v = q * 512 + tid;              // 0..4095
        int z = v & 15;
        int y = (v >> 4) & 15;
        int x = v >> 8;
        int l = (x * 16 + y) * 17 + z;
        size_t gaddr = ((size_t)((tx0 + x) * RES + (ty0 + y)) * RES
                        + (tz0 + z)) * 2;
        *reinterpret_cast<float2*>(grid + gaddr) =
            make_float2(acc[l], acc[TPLANE + l]);
    }
}

extern "C" void kernel_launch(void* const* d_in, const int* in_sizes, int n_in,
                              void* d_out, int out_size, void* d_ws, size_t ws_size,
                              hipStream_t stream) {
    const float* means      = (const float*)d_in[0];
    const float* opacities  = (const float*)d_in[1];
    const float* scales     = (const float*)d_in[2];
    const float* rotations  = (const float*)d_in[3];
    const float* phases     = (const float*)d_in[4];
    const float* phases_add = (const float*)d_in[5];
    float* grid = (float*)d_out;

    int N = in_sizes[1];
    int nb = (N + 255) / 256;

    // ws layout (~10.2 MB)
    char* p = (char*)d_ws;
    float*    rec     = (float*)p;     p += (size_t)N * RECSZ * sizeof(float);
    int*      homecnt = (int*)p;       p += (size_t)NTILE * sizeof(int);
    unsigned* hpb     = (unsigned*)p;  p += (size_t)NTILE * HCAP * sizeof(unsigned);
    int*      hlist   = (int*)p;

    (void)hipMemsetAsync(homecnt, 0, (size_t)NTILE * sizeof(int), stream);
    cgr_build<<<nb, 256, 0, stream>>>(means, opacities, scales, rotations,
                                      phases, phases_add, rec, homecnt,
                                      hpb, hlist, N);
    // one 512-thread block per 16^3 tile
    cgr_splat<<<512, 512, 0, stream>>>(rec, homecnt, hpb, hlist, grid);
}

// Round 16
// 93.419 us; speedup vs baseline: 3.7545x; 3.7545x over previous
//
#include <hip/hip_runtime.h>
#include <math.h>

// ComplexGaussianRasterizer — home-bucket bin + fused pull-scan voxel-gather,
// candidate-PAIR packed-f32 evaluation (round-12 structure, packed inner loop).
// 3 nodes:
//   memset:  zero homecnt (128 KB).
//   K1 build: per gaussian -> 48B record at rec[g] (coalesced); append
//             (pb, id) to its 4^3 home cell's fixed-HCAP bucket (1 atomic).
//   K2 eval:  one wave per 4^3 subtile, one voxel per lane. Wave pulls the 27
//             neighbor homes' (pb,id) slots, window-tests, ballot-compacts ids
//             into wave-private LDS. Staging writes records PAIR-TRANSPOSED
//             ({cA,cB} adjacent per component); inner loop reads 6 uniform
//             ds_read_b128 per pair -> f32x2 operands, evaluates the quadratic
//             for TWO candidates via v_pk_fma_f32, scalar in-test + exp2 each.
//             Odd tail padded with a never-in-footprint dummy record.

#define RES    128
#define NSBA   32
#define NTILE  (NSBA * NSBA * NSBA)   // 32768 home cells
#define RECSZ  12                     // floats per record (48 B)
#define HCAP   20                     // home-bucket capacity (lambda ~3.05)
#define CAP    96                     // per-subtile candidate cap (lambda ~35)
#define PSTR   24                     // floats per pair slot (12 comps x 2)

typedef float f32x2 __attribute__((ext_vector_type(2)));

// ---------------- record builder (quad coeffs scaled by log2e) -------------
__device__ __forceinline__ void build_record_at(
    const float* means, const float* opacities, const float* scales,
    const float* rotations, const float* phases, const float* phases_add,
    float* recdst, int g, int* bxo, int* byo, int* bzo)
{
    const float LB   = -1.0f;
    const float VOX  = 2.0f / 128.0f;
    const float L2E  = 1.4426950408889634f;

    float mx = means[g*3+0], my = means[g*3+1], mz = means[g*3+2];
    float op = opacities[g];
    float sx = scales[g*3+0], sy = scales[g*3+1], sz = scales[g*3+2];
    float qw = rotations[g*4+0], qx = rotations[g*4+1],
          qy = rotations[g*4+2], qz = rotations[g*4+3];
    float ph = phases[g], pa = phases_add[g];

    float qn = rsqrtf(qw*qw + qx*qx + qy*qy + qz*qz);
    qw *= qn; qx *= qn; qy *= qn; qz *= qn;

    float r00 = 1.0f - 2.0f*(qy*qy + qz*qz);
    float r01 = 2.0f*(qx*qy - qw*qz);
    float r02 = 2.0f*(qx*qz + qw*qy);
    float r10 = 2.0f*(qx*qy + qw*qz);
    float r11 = 1.0f - 2.0f*(qx*qx + qz*qz);
    float r12 = 2.0f*(qy*qz - qw*qx);
    float r20 = 2.0f*(qx*qz - qw*qy);
    float r21 = 2.0f*(qy*qz + qw*qx);
    float r22 = 1.0f - 2.0f*(qx*qx + qy*qy);

    float m00 = r00*sx, m01 = r01*sy, m02 = r02*sz;
    float m10 = r10*sx, m11 = r11*sy, m12 = r12*sz;
    float m20 = r20*sx, m21 = r21*sy, m22 = r22*sz;

    float a = m00*m00 + m01*m01 + m02*m02;
    float b = m00*m10 + m01*m11 + m02*m12;
    float c = m00*m20 + m01*m21 + m02*m22;
    float d = m10*m10 + m11*m11 + m12*m12;
    float e = m10*m20 + m11*m21 + m12*m22;
    float f = m20*m20 + m21*m21 + m22*m22;

    float A = d*f - e*e;
    float B = c*e - b*f;
    float C = b*e - c*d;
    float det  = a*A + b*B + c*C;
    float idet = L2E / det;            // fold log2e into all quad coeffs

    float n00 = -0.5f * A * idet;
    float n01 = -B * idet;
    float n02 = -C * idet;
    float n11 = -0.5f * (a*f - c*c) * idet;
    float n12 = -(b*c - a*e) * idet;
    float n22 = -0.5f * (a*d - b*b) * idet;

    int bx = (int)floorf((mx - LB) * 64.0f) - 3;
    int by = (int)floorf((my - LB) * 64.0f) - 3;
    int bz = (int)floorf((mz - LB) * 64.0f) - 3;
    unsigned pb = ((unsigned)(bx + 4) << 16) | ((unsigned)(by + 4) << 8) |
                  (unsigned)(bz + 4);

    float sr, cr;
    __sincosf(ph, &sr, &cr);
    float wr = op * cr;
    float wi = op * (sr + pa);

    float fx = LB + 0.5f * VOX - mx;
    float fy = LB + 0.5f * VOX - my;
    float fz = LB + 0.5f * VOX - mz;

    float4* rp = reinterpret_cast<float4*>(recdst);
    rp[0] = make_float4(n00, n01, n02, n11);
    rp[1] = make_float4(n12, n22, fx, fy);
    rp[2] = make_float4(fz, wr, wi, __uint_as_float(pb));
    *bxo = bx; *byo = by; *bzo = bz;
}

// ---------------- K1: build records + home-bucket append ----------------
__global__ __launch_bounds__(256) void cgr_build(
    const float* __restrict__ means, const float* __restrict__ opacities,
    const float* __restrict__ scales, const float* __restrict__ rotations,
    const float* __restrict__ phases, const float* __restrict__ phases_add,
    float* __restrict__ rec, int* __restrict__ homecnt,
    unsigned* __restrict__ hpb, int* __restrict__ hlist, int N)
{
    int g = blockIdx.x * 256 + threadIdx.x;
    if (g >= N) return;
    int bx, by, bz;
    build_record_at(means, opacities, scales, rotations, phases, phases_add,
                    rec + (size_t)g * RECSZ, g, &bx, &by, &bz);
    unsigned pb = ((unsigned)(bx + 4) << 16) | ((unsigned)(by + 4) << 8) |
                  (unsigned)(bz + 4);
    int hx = min(max(bx, 0), RES - 1) >> 2;
    int hy = min(max(by, 0), RES - 1) >> 2;
    int hz = min(max(bz, 0), RES - 1) >> 2;
    int h = (hx * NSBA + hy) * NSBA + hz;
    int slot = atomicAdd(&homecnt[h], 1);
    if (slot < HCAP) {
        hpb[h * HCAP + slot]   = pb;
        hlist[h * HCAP + slot] = g;
    }
}

// ---------------- K2: fused candidate-pull + paired packed eval ------------
__global__ __launch_bounds__(256) void cgr_eval(
    const float* __restrict__ rec,
    const int* __restrict__ homecnt,
    const unsigned* __restrict__ hpb,
    const int* __restrict__ hlist,
    float* __restrict__ grid)
{
    __shared__ __align__(16) float sbuf[4][32 * PSTR]; // pair-transposed recs
    __shared__ int idbuf[4][CAP];                      // candidate ids

    const float VOXC = 2.0f / 128.0f;

    int bid = blockIdx.x;
    int swz = (bid & 7) * 1024 + (bid >> 3);   // XCD-chunked swizzle

    int wave = threadIdx.x >> 6;
    int lane = threadIdx.x & 63;
    int s = swz * 4 + wave;                 // 0..NTILE-1
    int sx = s >> 10;
    int sy = (s >> 5) & 31;
    int sz = s & 31;
    int vx = sx * 4 + (lane >> 4);
    int vy = sy * 4 + ((lane >> 2) & 3);
    int vz = sz * 4 + (lane & 3);
    float fvx = (float)vx, fvy = (float)vy, fvz = (float)vz;
    int vxp4 = vx + 4, vyp4 = vy + 4, vzp4 = vz + 4;

    f32x2 fvx2 = {fvx, fvx}, fvy2 = {fvy, fvy}, fvz2 = {fvz, fvz};
    f32x2 voxc2 = {VOXC, VOXC};

    // base-window test constants: overlap iff pb_field - (4s-1) in [0,8]
    int x0 = 4 * sx - 1, y0 = 4 * sy - 1, z0 = 4 * sz - 1;

    // --- load 27 neighbor-home counts (lanes 0..26) ---
    int cnt_l = 0, hadr_l = 0;
    if (lane < 27) {
        int dx2 = lane / 9;
        int rem = lane - dx2 * 9;
        int dy2 = rem / 3;
        int dz2 = rem - dy2 * 3;
        int hx = sx + dx2 - 2, hy = sy + dy2 - 2, hz = sz + dz2 - 2;
        bool v = (hx >= 0) & (hy >= 0) & (hz >= 0);
        int hidx = v ? (hx * NSBA + hy) * NSBA + hz : 0;
        int c = homecnt[hidx];
        cnt_l  = v ? min(c, HCAP) : 0;
        hadr_l = hidx * HCAP;
    }

    int* idb = idbuf[wave];

    // --- scan slots: 9 iterations x (3 homes x 20 lanes); ballot-compact ---
    const int  grp  = lane / 20;            // 0..3 (lanes 60..63 idle)
    const int  slot = lane - grp * 20;
    const bool lv   = (grp < 3);
    int k = 0;
    #pragma unroll
    for (int it = 0; it < 9; ++it) {
        int hm   = lv ? (it * 3 + grp) : 0;
        int cnt  = __shfl(cnt_l, hm);
        int hadr = __shfl(hadr_l, hm);
        bool pass = lv & (slot < cnt);
        unsigned pb = 0u;
        int id = 0;
        if (pass) {
            pb = hpb[hadr + slot];
            id = hlist[hadr + slot];
        }
        if (pass) {
            pass = ((unsigned)((int)((pb >> 16) & 255u) - x0) <= 8u) &
                   ((unsigned)((int)((pb >> 8) & 255u)  - y0) <= 8u) &
                   ((unsigned)((int)(pb & 255u)         - z0) <= 8u);
        }
        unsigned long long mm = __ballot(pass);
        if (pass) {
            int pos = k + (int)__popcll(mm & ((1ull << lane) - 1ull));
            if (pos < CAP) idb[pos] = id;
        }
        k += (int)__popcll(mm);
    }
    int n = min(k, CAP);

    // --- stage (pair-transposed) + paired packed evaluate ---
    float* sb = sbuf[wave];
    float accR = 0.0f, accI = 0.0f;

    for (int cs = 0; cs < n; cs += 64) {
        int m = min(64, n - cs);
        if (lane < m) {
            int id = idb[cs + lane];
            const float4* rp =
                reinterpret_cast<const float4*>(rec + (size_t)id * RECSZ);
            float4 v0 = rp[0], v1 = rp[1], v2 = rp[2];
            float* d = sb + (lane >> 1) * PSTR + (lane & 1);
            d[0]  = v0.x; d[2]  = v0.y; d[4]  = v0.z; d[6]  = v0.w;
            d[8]  = v1.x; d[10] = v1.y; d[12] = v1.z; d[14] = v1.w;
            d[16] = v2.x; d[18] = v2.y; d[20] = v2.z; d[22] = v2.w;
        }
        int mp = m;
        if (m & 1) {
            if (lane == m) {        // dummy record: never in-footprint, w=0
                float* d = sb + (m >> 1) * PSTR + 1;
                #pragma unroll
                for (int c = 0; c < 11; ++c) d[c * 2] = 0.0f;
                d[22] = __uint_as_float(0x00FFFFFFu);   // pb: px=255
            }
            mp = m + 1;
        }
        // wave-private LDS: no barrier needed (per-wave program order)
        #pragma unroll 2
        for (int pr = 0; pr < (mp >> 1); ++pr) {
            const float4* q =
                reinterpret_cast<const float4*>(sb + pr * PSTR);
            float4 q0 = q[0], q1 = q[1], q2 = q[2];
            float4 q3 = q[3], q4 = q[4], q5 = q[5];

            f32x2 n00 = {q0.x, q0.y}, n01 = {q0.z, q0.w};
            f32x2 n02 = {q1.x, q1.y}, n11 = {q1.z, q1.w};
            f32x2 n12 = {q2.x, q2.y}, n22 = {q2.z, q2.w};
            f32x2 fx2 = {q3.x, q3.y}, fy2 = {q3.z, q3.w};
            f32x2 fz2 = {q4.x, q4.y};
            float wrA = q4.z, wrB = q4.w;
            float wiA = q5.x, wiB = q5.y;
            unsigned pbA = __float_as_uint(q5.z);
            unsigned pbB = __float_as_uint(q5.w);

            f32x2 dx2 = __builtin_elementwise_fma(fvx2, voxc2, fx2);
            f32x2 dy2 = __builtin_elementwise_fma(fvy2, voxc2, fy2);
            f32x2 dz2 = __builtin_elementwise_fma(fvz2, voxc2, fz2);

            f32x2 t = __builtin_elementwise_fma(n01, dy2, n00 * dx2);
            t = __builtin_elementwise_fma(n02, dz2, t);
            f32x2 u = __builtin_elementwise_fma(n12, dz2, n11 * dy2);
            f32x2 arg = __builtin_elementwise_fma(
                dz2, n22 * dz2,
                __builtin_elementwise_fma(dy2, u, dx2 * t));

            unsigned uxA = (unsigned)(vxp4 - (int)(pbA >> 16));
            unsigned uyA = (unsigned)(vyp4 - (int)((pbA >> 8) & 255u));
            unsigned uzA = (unsigned)(vzp4 - (int)(pbA & 255u));
            bool inA = max(max(uxA, uyA), uzA) < 6u;
            unsigned uxB = (unsigned)(vxp4 - (int)(pbB >> 16));
            unsigned uyB = (unsigned)(vyp4 - (int)((pbB >> 8) & 255u));
            unsigned uzB = (unsigned)(vzp4 - (int)(pbB & 255u));
            bool inB = max(max(uxB, uyB), uzB) < 6u;

            float wA = inA ? exp2f(arg.x) : 0.0f;
            float wB = inB ? exp2f(arg.y) : 0.0f;
            accR = fmaf(wA, wrA, fmaf(wB, wrB, accR));
            accI = fmaf(wA, wiA, fmaf(wB, wiB, accI));
        }
    }

    size_t addr = ((size_t)(vx * RES + vy) * RES + vz) * 2;
    *reinterpret_cast<float2*>(grid + addr) = make_float2(accR, accI);
}

extern "C" void kernel_launch(void* const* d_in, const int* in_sizes, int n_in,
                              void* d_out, int out_size, void* d_ws, size_t ws_size,
                              hipStream_t stream) {
    const float* means      = (const float*)d_in[0];
    const float* opacities  = (const float*)d_in[1];
    const float* scales     = (const float*)d_in[2];
    const float* rotations  = (const float*)d_in[3];
    const float* phases     = (const float*)d_in[4];
    const float* phases_add = (const float*)d_in[5];
    float* grid = (float*)d_out;

    int N = in_sizes[1];
    int nb = (N + 255) / 256;

    // ws layout (~10.2 MB)
    char* p = (char*)d_ws;
    float*    rec     = (float*)p;     p += (size_t)N * RECSZ * sizeof(float);
    int*      homecnt = (int*)p;       p += (size_t)NTILE * sizeof(int);
    unsigned* hpb     = (unsigned*)p;  p += (size_t)NTILE * HCAP * sizeof(unsigned);
    int*      hlist   = (int*)p;

    (void)hipMemsetAsync(homecnt, 0, (size_t)NTILE * sizeof(int), stream);
    cgr_build<<<nb, 256, 0, stream>>>(means, opacities, scales, rotations,
                                      phases, phases_add, rec, homecnt,
                                      hpb, hlist, N);
    cgr_eval<<<NTILE / 4, 256, 0, stream>>>(rec, homecnt, hpb, hlist, grid);
}

// Round 17
// 90.541 us; speedup vs baseline: 3.8738x; 1.0318x over previous
//
#include <hip/hip_runtime.h>
#include <math.h>

// ComplexGaussianRasterizer — home-bucket bin + fused pull-scan voxel-gather,
// candidate-pair packed-f32 eval with COMPONENT-MAJOR LDS staging.
// 3 nodes:
//   memset:  zero homecnt (128 KB).
//   K1 build: per gaussian -> 48B record at rec[g] (coalesced); append
//             (pb, id) to its 4^3 home cell's fixed-HCAP bucket (1 atomic).
//   K2 eval:  one wave per 4^3 subtile, one voxel per lane. Wave pulls the 27
//             neighbor homes' (pb,id) slots, window-tests, ballot-compacts ids
//             into wave-private LDS. Staging is component-major
//             (sb[c*64 + cand]): 64 consecutive writes per component -> ZERO
//             bank conflicts; a float4 read at c*64+4t serves 4 candidates.
//             Inner loop: 12 b128 broadcast reads per 4 candidates (2 pairs),
//             v_pk_fma_f32 quadratic per pair, scalar in-test + exp2 each.
//             Tail padded to multiple of 4 with never-in-footprint dummies.

#define RES    128
#define NSBA   32
#define NTILE  (NSBA * NSBA * NSBA)   // 32768 home cells
#define RECSZ  12                     // floats per record (48 B)
#define HCAP   20                     // home-bucket capacity (lambda ~3.05)
#define CAP    96                     // per-subtile candidate cap (lambda ~35)

typedef float f32x2 __attribute__((ext_vector_type(2)));

// ---------------- record builder (quad coeffs scaled by log2e) -------------
__device__ __forceinline__ void build_record_at(
    const float* means, const float* opacities, const float* scales,
    const float* rotations, const float* phases, const float* phases_add,
    float* recdst, int g, int* bxo, int* byo, int* bzo)
{
    const float LB   = -1.0f;
    const float VOX  = 2.0f / 128.0f;
    const float L2E  = 1.4426950408889634f;

    float mx = means[g*3+0], my = means[g*3+1], mz = means[g*3+2];
    float op = opacities[g];
    float sx = scales[g*3+0], sy = scales[g*3+1], sz = scales[g*3+2];
    float qw = rotations[g*4+0], qx = rotations[g*4+1],
          qy = rotations[g*4+2], qz = rotations[g*4+3];
    float ph = phases[g], pa = phases_add[g];

    float qn = rsqrtf(qw*qw + qx*qx + qy*qy + qz*qz);
    qw *= qn; qx *= qn; qy *= qn; qz *= qn;

    float r00 = 1.0f - 2.0f*(qy*qy + qz*qz);
    float r01 = 2.0f*(qx*qy - qw*qz);
    float r02 = 2.0f*(qx*qz + qw*qy);
    float r10 = 2.0f*(qx*qy + qw*qz);
    float r11 = 1.0f - 2.0f*(qx*qx + qz*qz);
    float r12 = 2.0f*(qy*qz - qw*qx);
    float r20 = 2.0f*(qx*qz - qw*qy);
    float r21 = 2.0f*(qy*qz + qw*qx);
    float r22 = 1.0f - 2.0f*(qx*qx + qy*qy);

    float m00 = r00*sx, m01 = r01*sy, m02 = r02*sz;
    float m10 = r10*sx, m11 = r11*sy, m12 = r12*sz;
    float m20 = r20*sx, m21 = r21*sy, m22 = r22*sz;

    float a = m00*m00 + m01*m01 + m02*m02;
    float b = m00*m10 + m01*m11 + m02*m12;
    float c = m00*m20 + m01*m21 + m02*m22;
    float d = m10*m10 + m11*m11 + m12*m12;
    float e = m10*m20 + m11*m21 + m12*m22;
    float f = m20*m20 + m21*m21 + m22*m22;

    float A = d*f - e*e;
    float B = c*e - b*f;
    float C = b*e - c*d;
    float det  = a*A + b*B + c*C;
    float idet = L2E / det;            // fold log2e into all quad coeffs

    float n00 = -0.5f * A * idet;
    float n01 = -B * idet;
    float n02 = -C * idet;
    float n11 = -0.5f * (a*f - c*c) * idet;
    float n12 = -(b*c - a*e) * idet;
    float n22 = -0.5f * (a*d - b*b) * idet;

    int bx = (int)floorf((mx - LB) * 64.0f) - 3;
    int by = (int)floorf((my - LB) * 64.0f) - 3;
    int bz = (int)floorf((mz - LB) * 64.0f) - 3;
    unsigned pb = ((unsigned)(bx + 4) << 16) | ((unsigned)(by + 4) << 8) |
                  (unsigned)(bz + 4);

    float sr, cr;
    __sincosf(ph, &sr, &cr);
    float wr = op * cr;
    float wi = op * (sr + pa);

    float fx = LB + 0.5f * VOX - mx;
    float fy = LB + 0.5f * VOX - my;
    float fz = LB + 0.5f * VOX - mz;

    float4* rp = reinterpret_cast<float4*>(recdst);
    rp[0] = make_float4(n00, n01, n02, n11);
    rp[1] = make_float4(n12, n22, fx, fy);
    rp[2] = make_float4(fz, wr, wi, __uint_as_float(pb));
    *bxo = bx; *byo = by; *bzo = bz;
}

// ---------------- K1: build records + home-bucket append ----------------
__global__ __launch_bounds__(256) void cgr_build(
    const float* __restrict__ means, const float* __restrict__ opacities,
    const float* __restrict__ scales, const float* __restrict__ rotations,
    const float* __restrict__ phases, const float* __restrict__ phases_add,
    float* __restrict__ rec, int* __restrict__ homecnt,
    unsigned* __restrict__ hpb, int* __restrict__ hlist, int N)
{
    int g = blockIdx.x * 256 + threadIdx.x;
    if (g >= N) return;
    int bx, by, bz;
    build_record_at(means, opacities, scales, rotations, phases, phases_add,
                    rec + (size_t)g * RECSZ, g, &bx, &by, &bz);
    unsigned pb = ((unsigned)(bx + 4) << 16) | ((unsigned)(by + 4) << 8) |
                  (unsigned)(bz + 4);
    int hx = min(max(bx, 0), RES - 1) >> 2;
    int hy = min(max(by, 0), RES - 1) >> 2;
    int hz = min(max(bz, 0), RES - 1) >> 2;
    int h = (hx * NSBA + hy) * NSBA + hz;
    int slot = atomicAdd(&homecnt[h], 1);
    if (slot < HCAP) {
        hpb[h * HCAP + slot]   = pb;
        hlist[h * HCAP + slot] = g;
    }
}

// evaluate one candidate pair from component float4s (S0/S1 select the pair)
#define EVAL_PAIR(S0, S1)                                                     \
    do {                                                                      \
        f32x2 pn00 = {c_n00.S0, c_n00.S1};                                    \
        f32x2 pn01 = {c_n01.S0, c_n01.S1};                                    \
        f32x2 pn02 = {c_n02.S0, c_n02.S1};                                    \
        f32x2 pn11 = {c_n11.S0, c_n11.S1};                                    \
        f32x2 pn12 = {c_n12.S0, c_n12.S1};                                    \
        f32x2 pn22 = {c_n22.S0, c_n22.S1};                                    \
        f32x2 pfx  = {c_fx.S0,  c_fx.S1};                                     \
        f32x2 pfy  = {c_fy.S0,  c_fy.S1};                                     \
        f32x2 pfz  = {c_fz.S0,  c_fz.S1};                                     \
        f32x2 dxp = __builtin_elementwise_fma(fvx2, voxc2, pfx);              \
        f32x2 dyp = __builtin_elementwise_fma(fvy2, voxc2, pfy);              \
        f32x2 dzp = __builtin_elementwise_fma(fvz2, voxc2, pfz);              \
        f32x2 t0 = __builtin_elementwise_fma(pn01, dyp, pn00 * dxp);          \
        t0 = __builtin_elementwise_fma(pn02, dzp, t0);                        \
        f32x2 u0 = __builtin_elementwise_fma(pn12, dzp, pn11 * dyp);          \
        f32x2 arg = __builtin_elementwise_fma(                                \
            dzp, pn22 * dzp,                                                  \
            __builtin_elementwise_fma(dyp, u0, dxp * t0));                    \
        unsigned pbA = __float_as_uint(c_pb.S0);                              \
        unsigned pbB = __float_as_uint(c_pb.S1);                              \
        unsigned uxA = (unsigned)(vxp4 - (int)(pbA >> 16));                   \
        unsigned uyA = (unsigned)(vyp4 - (int)((pbA >> 8) & 255u));           \
        unsigned uzA = (unsigned)(vzp4 - (int)(pbA & 255u));                  \
        bool inA = max(max(uxA, uyA), uzA) < 6u;                              \
        unsigned uxB = (unsigned)(vxp4 - (int)(pbB >> 16));                   \
        unsigned uyB = (unsigned)(vyp4 - (int)((pbB >> 8) & 255u));           \
        unsigned uzB = (unsigned)(vzp4 - (int)(pbB & 255u));                  \
        bool inB = max(max(uxB, uyB), uzB) < 6u;                              \
        float wA = inA ? exp2f(arg.x) : 0.0f;                                 \
        float wB = inB ? exp2f(arg.y) : 0.0f;                                 \
        accR = fmaf(wA, c_wr.S0, fmaf(wB, c_wr.S1, accR));                    \
        accI = fmaf(wA, c_wi.S0, fmaf(wB, c_wi.S1, accI));                    \
    } while (0)

// ---------------- K2: fused candidate-pull + paired packed eval ------------
__global__ __launch_bounds__(256) void cgr_eval(
    const float* __restrict__ rec,
    const int* __restrict__ homecnt,
    const unsigned* __restrict__ hpb,
    const int* __restrict__ hlist,
    float* __restrict__ grid)
{
    __shared__ __align__(16) float sbuf[4][12 * 64];   // component-major recs
    __shared__ int idbuf[4][CAP];                      // candidate ids

    const float VOXC = 2.0f / 128.0f;

    int bid = blockIdx.x;
    int swz = (bid & 7) * 1024 + (bid >> 3);   // XCD-chunked swizzle

    int wave = threadIdx.x >> 6;
    int lane = threadIdx.x & 63;
    int s = swz * 4 + wave;                 // 0..NTILE-1
    int sx = s >> 10;
    int sy = (s >> 5) & 31;
    int sz = s & 31;
    int vx = sx * 4 + (lane >> 4);
    int vy = sy * 4 + ((lane >> 2) & 3);
    int vz = sz * 4 + (lane & 3);
    float fvx = (float)vx, fvy = (float)vy, fvz = (float)vz;
    int vxp4 = vx + 4, vyp4 = vy + 4, vzp4 = vz + 4;

    f32x2 fvx2 = {fvx, fvx}, fvy2 = {fvy, fvy}, fvz2 = {fvz, fvz};
    f32x2 voxc2 = {VOXC, VOXC};

    // base-window test constants: overlap iff pb_field - (4s-1) in [0,8]
    int x0 = 4 * sx - 1, y0 = 4 * sy - 1, z0 = 4 * sz - 1;

    // --- load 27 neighbor-home counts (lanes 0..26) ---
    int cnt_l = 0, hadr_l = 0;
    if (lane < 27) {
        int dx2 = lane / 9;
        int rem = lane - dx2 * 9;
        int dy2 = rem / 3;
        int dz2 = rem - dy2 * 3;
        int hx = sx + dx2 - 2, hy = sy + dy2 - 2, hz = sz + dz2 - 2;
        bool v = (hx >= 0) & (hy >= 0) & (hz >= 0);
        int hidx = v ? (hx * NSBA + hy) * NSBA + hz : 0;
        int c = homecnt[hidx];
        cnt_l  = v ? min(c, HCAP) : 0;
        hadr_l = hidx * HCAP;
    }

    int* idb = idbuf[wave];

    // --- scan slots: 9 iterations x (3 homes x 20 lanes); ballot-compact ---
    const int  grp  = lane / 20;            // 0..3 (lanes 60..63 idle)
    const int  slot = lane - grp * 20;
    const bool lv   = (grp < 3);
    int k = 0;
    #pragma unroll
    for (int it = 0; it < 9; ++it) {
        int hm   = lv ? (it * 3 + grp) : 0;
        int cnt  = __shfl(cnt_l, hm);
        int hadr = __shfl(hadr_l, hm);
        bool pass = lv & (slot < cnt);
        unsigned pb = 0u;
        int id = 0;
        if (pass) {
            pb = hpb[hadr + slot];
            id = hlist[hadr + slot];
        }
        if (pass) {
            pass = ((unsigned)((int)((pb >> 16) & 255u) - x0) <= 8u) &
                   ((unsigned)((int)((pb >> 8) & 255u)  - y0) <= 8u) &
                   ((unsigned)((int)(pb & 255u)         - z0) <= 8u);
        }
        unsigned long long mm = __ballot(pass);
        if (pass) {
            int pos = k + (int)__popcll(mm & ((1ull << lane) - 1ull));
            if (pos < CAP) idb[pos] = id;
        }
        k += (int)__popcll(mm);
    }
    int n = min(k, CAP);

    // --- stage (component-major) + paired packed evaluate ---
    float* sb = sbuf[wave];
    float accR = 0.0f, accI = 0.0f;

    for (int cs = 0; cs < n; cs += 64) {
        int m = min(64, n - cs);
        int mp4 = (m + 3) & ~3;             // pad to multiple of 4 candidates
        if (lane < m) {
            int id = idb[cs + lane];
            const float4* rp =
                reinterpret_cast<const float4*>(rec + (size_t)id * RECSZ);
            float4 v0 = rp[0], v1 = rp[1], v2 = rp[2];
            float* d = sb + lane;           // stride-64 per component: no
            d[0*64]  = v0.x; d[1*64]  = v0.y;   // bank conflicts (64 lanes
            d[2*64]  = v0.z; d[3*64]  = v0.w;   // hit consecutive words)
            d[4*64]  = v1.x; d[5*64]  = v1.y;
            d[6*64]  = v1.z; d[7*64]  = v1.w;
            d[8*64]  = v2.x; d[9*64]  = v2.y;
            d[10*64] = v2.z; d[11*64] = v2.w;
        } else if (lane < mp4) {            // dummy: never in-footprint, w=0
            float* d = sb + lane;
            #pragma unroll
            for (int c = 0; c < 11; ++c) d[c * 64] = 0.0f;
            d[11 * 64] = __uint_as_float(0x00FFFFFFu);
        }
        // wave-private LDS: no barrier needed (per-wave program order)
        for (int t = 0; t < (mp4 >> 2); ++t) {
            const float* bp = sb + 4 * t;   // 4 candidates per iteration
            float4 c_n00 = *reinterpret_cast<const float4*>(bp + 0*64);
            float4 c_n01 = *reinterpret_cast<const float4*>(bp + 1*64);
            float4 c_n02 = *reinterpret_cast<const float4*>(bp + 2*64);
            float4 c_n11 = *reinterpret_cast<const float4*>(bp + 3*64);
            float4 c_n12 = *reinterpret_cast<const float4*>(bp + 4*64);
            float4 c_n22 = *reinterpret_cast<const float4*>(bp + 5*64);
            float4 c_fx  = *reinterpret_cast<const float4*>(bp + 6*64);
            float4 c_fy  = *reinterpret_cast<const float4*>(bp + 7*64);
            float4 c_fz  = *reinterpret_cast<const float4*>(bp + 8*64);
            float4 c_wr  = *reinterpret_cast<const float4*>(bp + 9*64);
            float4 c_wi  = *reinterpret_cast<const float4*>(bp + 10*64);
            float4 c_pb  = *reinterpret_cast<const float4*>(bp + 11*64);
            EVAL_PAIR(x, y);                // candidates 4t, 4t+1
            EVAL_PAIR(z, w);                // candidates 4t+2, 4t+3
        }
    }

    size_t addr = ((size_t)(vx * RES + vy) * RES + vz) * 2;
    *reinterpret_cast<float2*>(grid + addr) = make_float2(accR, accI);
}

extern "C" void kernel_launch(void* const* d_in, const int* in_sizes, int n_in,
                              void* d_out, int out_size, void* d_ws, size_t ws_size,
                              hipStream_t stream) {
    const float* means      = (const float*)d_in[0];
    const float* opacities  = (const float*)d_in[1];
    const float* scales     = (const float*)d_in[2];
    const float* rotations  = (const float*)d_in[3];
    const float* phases     = (const float*)d_in[4];
    const float* phases_add = (const float*)d_in[5];
    float* grid = (float*)d_out;

    int N = in_sizes[1];
    int nb = (N + 255) / 256;

    // ws layout (~10.2 MB)
    char* p = (char*)d_ws;
    float*    rec     = (float*)p;     p += (size_t)N * RECSZ * sizeof(float);
    int*      homecnt = (int*)p;       p += (size_t)NTILE * sizeof(int);
    unsigned* hpb     = (unsigned*)p;  p += (size_t)NTILE * HCAP * sizeof(unsigned);
    int*      hlist   = (int*)p;

    (void)hipMemsetAsync(homecnt, 0, (size_t)NTILE * sizeof(int), stream);
    cgr_build<<<nb, 256, 0, stream>>>(means, opacities, scales, rotations,
                                      phases, phases_add, rec, homecnt,
                                      hpb, hlist, N);
    cgr_eval<<<NTILE / 4, 256, 0, stream>>>(rec, homecnt, hpb, hlist, grid);
}